// Round 7
// baseline (808.834 us; speedup 1.0000x reference)
//
#include <hip/hip_runtime.h>
#include <hip/hip_bf16.h>

#define M_TOT 8192
#define N_TOT 16384
#define K_TOT 4096
#define BM 128
#define BN 256
#define BK 64
#define NT (K_TOT / BK)  // 64 K-tiles

typedef int i32x4 __attribute__((ext_vector_type(4)));
typedef int i32x16 __attribute__((ext_vector_type(16)));
typedef __bf16 bf16x8 __attribute__((ext_vector_type(8)));
typedef float f32x4 __attribute__((ext_vector_type(4)));

#define GLOAD_LDS16(g, l)                                                     \
  __builtin_amdgcn_global_load_lds(                                           \
      (__attribute__((address_space(1))) const void*)(g),                     \
      (__attribute__((address_space(3))) void*)(l), 16, 0, 0)

__device__ __forceinline__ ushort f2bf_rne(float f) {
  unsigned u = __float_as_uint(f);
  u += 0x7FFFu + ((u >> 16) & 1u);
  return (ushort)(u >> 16);
}
__device__ __forceinline__ ushort sgn_bf16(float w) {
  return w > 0.f ? (ushort)0x3F80u : (w < 0.f ? (ushort)0xBF80u : (ushort)0u);
}

// ---------------- pass 1a: per-row amax + quantize x to i8 ----------------
__global__ void quant_x_kernel(const float* __restrict__ x,
                               char* __restrict__ xq, float* __restrict__ s) {
  int row = blockIdx.x;
  const float4* xr = (const float4*)(x + (size_t)row * K_TOT);
  int tid = threadIdx.x;
  float4 v[4];
  float amax = 0.f;
#pragma unroll
  for (int j = 0; j < 4; ++j) {
    v[j] = xr[j * 256 + tid];
    amax = fmaxf(amax, fmaxf(fmaxf(fabsf(v[j].x), fabsf(v[j].y)),
                             fmaxf(fabsf(v[j].z), fabsf(v[j].w))));
  }
#pragma unroll
  for (int o = 32; o > 0; o >>= 1) amax = fmaxf(amax, __shfl_xor(amax, o));
  __shared__ float wmax[4];
  if ((tid & 63) == 0) wmax[tid >> 6] = amax;
  __syncthreads();
  amax = fmaxf(fmaxf(wmax[0], wmax[1]), fmaxf(wmax[2], wmax[3]));
  float inv = amax > 0.f ? 127.0f / amax : 0.f;
  if (tid == 0) s[row] = amax * (1.0f / 127.0f);
  int* out = (int*)(xq + (size_t)row * K_TOT);
#pragma unroll
  for (int j = 0; j < 4; ++j) {
    int q0 = max(-127, min(127, __float2int_rn(v[j].x * inv)));
    int q1 = max(-127, min(127, __float2int_rn(v[j].y * inv)));
    int q2 = max(-127, min(127, __float2int_rn(v[j].z * inv)));
    int q3 = max(-127, min(127, __float2int_rn(v[j].w * inv)));
    out[j * 256 + tid] =
        (q0 & 255) | ((q1 & 255) << 8) | ((q2 & 255) << 16) | ((q3 & 255) << 24);
  }
}

// ---------------- pass 1b: W -> sign in i8 ----------------
__global__ void quant_w_kernel(const float* __restrict__ w,
                               char* __restrict__ wq, int n4) {
  int i = blockIdx.x * blockDim.x + threadIdx.x;
  int stride = gridDim.x * blockDim.x;
  for (; i < n4; i += stride) {
    float4 v = ((const float4*)w)[i];
    int q0 = v.x > 0.f ? 1 : (v.x < 0.f ? -1 : 0);
    int q1 = v.y > 0.f ? 1 : (v.y < 0.f ? -1 : 0);
    int q2 = v.z > 0.f ? 1 : (v.z < 0.f ? -1 : 0);
    int q3 = v.w > 0.f ? 1 : (v.w < 0.f ? -1 : 0);
    ((int*)wq)[i] =
        (q0 & 255) | ((q1 & 255) << 8) | ((q2 & 255) << 16) | ((q3 & 255) << 24);
  }
}

// ---------------- pass 2: i8 GEMM, 2 blocks/CU, group-swizzled LDS ----------
// C[m][n] = s[m] * (sum_k A8[m][k]*W8[n][k]) + bias[n]   (i32 accum, exact)
// BM=128 BN=256 BK=64. 512 threads = 8 waves (2M x 4N), wave-tile 64x64.
// LDS: A[2][8KB] + B[2][16KB] = 48KB; 2 blocks/CU.
//
// GROUP-SWIZZLE (full-coverage layout): slab = 1024B groups, one group =
// (32-row-group rg, K-half ks): rows rg*32..+31, k-bytes ks*32..+31.
//   A group base = (ks*4 + rg)*1024;  B group base = (ks*8 + rg)*1024.
// Within a group, 16B chunk of data (r in 0..31, c in 0..1) lives at slot
//   (r&15)*4 + (((r>>4)|(c<<1)) ^ (((r&15)>>1)&3)).
// The 32x32x32-i8 frag read (row = lane&31, c = lane>>5) then covers every
// group exactly once per ds_read_b128, quarter-by-quarter BYTE-IDENTICAL to
// the round-3 pattern that measured SQ_LDS_BANK_CONFLICT = 0.
// gload_lds dest stays linear (slot = tid); the permutation is applied to
// the per-lane GLOBAL source address (both-sides rule).
// Schedule per tile t (buf b=t&1): 8 reads + 8 MFMA; bar; STAGE(t+2 -> b);
// vmcnt(3) [tile t+1 landed; t+2 stays in flight]; bar.
__global__ __launch_bounds__(512, 4) void gemm_i8_dual(
    const char* __restrict__ A, const char* __restrict__ B,
    const float* __restrict__ s, const float* __restrict__ bias,
    float* __restrict__ C) {
  __shared__ char ldsA[2][128 * 64];
  __shared__ char ldsB[2][256 * 64];

  // XCD supertile swizzle (4096 blocks): each XCD gets one bn stripe
  // (8 bn cols x all 64 bm rows).
  int bid = blockIdx.x;
  int wg = (bid & 7) * 512 + (bid >> 3);
  int bnSup = wg >> 9;
  int rem = wg & 511;
  int bm = rem >> 3;
  int bn = bnSup * 8 + (rem & 7);
  int rowBase = bm * BM;
  int colBase = bn * BN;

  int t = threadIdx.x;
  int lane = t & 63;
  int wave = t >> 6;
  int wr = wave >> 2;  // 0..1 -> M half (64)
  int wc = wave & 3;   // 0..3 -> N quarter (64)
  int l31 = lane & 31;
  int hi = lane >> 5;

  // ---- staging sources (inverse of the group-swizzle; dest = slot*16) ----
  // A slot t: group g = t>>6 (= ks*4+rg), in-group slot t&63.
  {
  }
  int gA_ks = (t >> 8) & 1;
  int gA_rg = (t >> 6) & 3;
  int vrowA = (t >> 2) & 15;
  int crawA = (t & 3) ^ ((t >> 3) & 3);
  int rA = gA_rg * 32 + vrowA + ((crawA & 1) << 4);
  int kA = gA_ks * 32 + ((crawA >> 1) << 4);
  const char* gA = A + (size_t)(rowBase + rA) * K_TOT + kA;

  // B slots t and t+512: group g = s>>6 (= ks*8+rg).
  int s0 = t, s1 = t + 512;
  int ks0_ = (s0 >> 9) & 1, rg0_ = (s0 >> 6) & 7;
  int vr0 = (s0 >> 2) & 15;
  int cr0 = (s0 & 3) ^ ((s0 >> 3) & 3);
  const char* gB0 = B + (size_t)(colBase + rg0_ * 32 + vr0 + ((cr0 & 1) << 4)) * K_TOT +
                    ks0_ * 32 + ((cr0 >> 1) << 4);
  int ks1_ = (s1 >> 9) & 1, rg1_ = (s1 >> 6) & 7;
  int vr1 = (s1 >> 2) & 15;
  int cr1 = (s1 & 3) ^ ((s1 >> 3) & 3);
  const char* gB1 = B + (size_t)(colBase + rg1_ * 32 + vr1 + ((cr1 & 1) << 4)) * K_TOT +
                    ks1_ * 32 + ((cr1 >> 1) << 4);
  int lt = t * 16;

  // ---- frag-read per-lane constant (in-group byte offset) ----
  int inb = ((((l31 & 15) << 2) |
              (((l31 >> 4) | (hi << 1)) ^ ((l31 >> 1) & 3)))) << 4;

  i32x16 acc[2][2] = {};

#define STAGE(kt_, buf_)                                                      \
  {                                                                           \
    size_t _o = (size_t)(kt_)*64;                                             \
    GLOAD_LDS16(gA + _o, &ldsA[buf_][lt]);                                    \
    GLOAD_LDS16(gB0 + _o, &ldsB[buf_][lt]);                                   \
    GLOAD_LDS16(gB1 + _o, &ldsB[buf_][8192 + lt]);                            \
  }

  // prologue: tiles 0 and 1
  STAGE(0, 0);
  STAGE(1, 1);
  asm volatile("s_waitcnt vmcnt(3)" ::: "memory");  // tile0 landed
  __builtin_amdgcn_s_barrier();

  for (int tt = 0; tt < NT; ++tt) {
    int b = tt & 1;
    const char* la = &ldsA[b][0];
    const char* lb = &ldsB[b][0];
    i32x4 af[2], bf[2];
    // ---- ks0 ----
    af[0] = *(const i32x4*)(la + (wr * 2 + 0) * 1024 + inb);
    af[1] = *(const i32x4*)(la + (wr * 2 + 1) * 1024 + inb);
    bf[0] = *(const i32x4*)(lb + (wc * 2 + 0) * 1024 + inb);
    bf[1] = *(const i32x4*)(lb + (wc * 2 + 1) * 1024 + inb);
    __builtin_amdgcn_s_setprio(1);
#pragma unroll
    for (int mi = 0; mi < 2; ++mi)
#pragma unroll
      for (int ni = 0; ni < 2; ++ni)
        acc[mi][ni] = __builtin_amdgcn_mfma_i32_32x32x32_i8(af[mi], bf[ni],
                                                            acc[mi][ni], 0, 0, 0);
    __builtin_amdgcn_s_setprio(0);
    // ---- ks1 ----
    af[0] = *(const i32x4*)(la + 4096 + (wr * 2 + 0) * 1024 + inb);
    af[1] = *(const i32x4*)(la + 4096 + (wr * 2 + 1) * 1024 + inb);
    bf[0] = *(const i32x4*)(lb + 8192 + (wc * 2 + 0) * 1024 + inb);
    bf[1] = *(const i32x4*)(lb + 8192 + (wc * 2 + 1) * 1024 + inb);
    __builtin_amdgcn_s_setprio(1);
#pragma unroll
    for (int mi = 0; mi < 2; ++mi)
#pragma unroll
      for (int ni = 0; ni < 2; ++ni)
        acc[mi][ni] = __builtin_amdgcn_mfma_i32_32x32x32_i8(af[mi], bf[ni],
                                                            acc[mi][ni], 0, 0, 0);
    __builtin_amdgcn_s_setprio(0);

    __builtin_amdgcn_s_barrier();  // all waves done reading buf b
    if (tt + 2 < NT) {
      STAGE(tt + 2, b);
      asm volatile("s_waitcnt vmcnt(3)" ::: "memory");  // tile t+1 landed
    } else if (tt + 1 < NT) {
      asm volatile("s_waitcnt vmcnt(0)" ::: "memory");
    }
    __builtin_amdgcn_s_barrier();  // buf b^1 ready
  }

#undef STAGE

  // epilogue: y = s[m] * acc + bias[n]
  // C/D 32x32: col = lane&31, row = (reg&3) + 8*(reg>>2) + 4*(lane>>5)
#pragma unroll
  for (int mi = 0; mi < 2; ++mi) {
#pragma unroll
    for (int ni = 0; ni < 2; ++ni) {
      int gc = colBase + wc * 64 + ni * 32 + l31;
      float bv = bias[gc];
#pragma unroll
      for (int rg = 0; rg < 16; ++rg) {
        int rowIn = (rg & 3) + 8 * (rg >> 2) + 4 * hi;
        int gr = rowBase + wr * 64 + mi * 32 + rowIn;
        C[(size_t)gr * N_TOT + gc] = (float)acc[mi][ni][rg] * s[gr] + bv;
      }
    }
  }
}

// ---------------- fallback (ws too small): fused bf16 conversion GEMM --------
__global__ void gemm_fused_kernel(const float* __restrict__ A,
                                  const float* __restrict__ W,
                                  const float* __restrict__ bias,
                                  float* __restrict__ C) {
  __shared__ ushort lsA[128 * 32];
  __shared__ ushort lsB[128 * 32];

  int nwg = gridDim.x;
  int bid = blockIdx.x;
  int wg = (bid & 7) * (nwg >> 3) + (bid >> 3);
  const int NBN = N_TOT / 128;
  int bm = wg / NBN;
  int bn = wg % NBN;
  int rowBase = bm * 128;
  int colBase = bn * 128;

  int t = threadIdx.x;
  int lane = t & 63;
  int wave = t >> 6;
  int wm = (wave >> 1) * 64;
  int wn = (wave & 1) * 64;

  f32x4 acc[4][4] = {};

  int srow = t >> 3;
  int scol = (t & 7) * 4;
  int fr = lane & 15;
  int koff = (lane >> 4) * 8;

  for (int k0 = 0; k0 < K_TOT; k0 += 32) {
    float4 va[4], vb[4];
#pragma unroll
    for (int r = 0; r < 4; ++r) {
      va[r] = *(const float4*)&A[(size_t)(rowBase + r * 32 + srow) * K_TOT + k0 + scol];
      vb[r] = *(const float4*)&W[(size_t)(colBase + r * 32 + srow) * K_TOT + k0 + scol];
    }
    __syncthreads();
#pragma unroll
    for (int r = 0; r < 4; ++r) {
      int e = r * 1024 + t * 4;
      ushort4 oa, ob;
      oa.x = f2bf_rne(va[r].x); oa.y = f2bf_rne(va[r].y);
      oa.z = f2bf_rne(va[r].z); oa.w = f2bf_rne(va[r].w);
      ob.x = sgn_bf16(vb[r].x); ob.y = sgn_bf16(vb[r].y);
      ob.z = sgn_bf16(vb[r].z); ob.w = sgn_bf16(vb[r].w);
      *(ushort4*)&lsA[e] = oa;
      *(ushort4*)&lsB[e] = ob;
    }
    __syncthreads();

    bf16x8 af[4], bfr[4];
#pragma unroll
    for (int i = 0; i < 4; ++i)
      af[i] = *(const bf16x8*)&lsA[(wm + i * 16 + fr) * 32 + koff];
#pragma unroll
    for (int j = 0; j < 4; ++j)
      bfr[j] = *(const bf16x8*)&lsB[(wn + j * 16 + fr) * 32 + koff];

#pragma unroll
    for (int i = 0; i < 4; ++i)
#pragma unroll
      for (int j = 0; j < 4; ++j)
        acc[i][j] = __builtin_amdgcn_mfma_f32_16x16x32_bf16(af[i], bfr[j],
                                                            acc[i][j], 0, 0, 0);
  }

  int orow0 = rowBase + wm + ((lane >> 4) << 2);
  int ocol0 = colBase + wn + (lane & 15);
#pragma unroll
  for (int i = 0; i < 4; ++i) {
#pragma unroll
    for (int j = 0; j < 4; ++j) {
      int col = ocol0 + j * 16;
      float bv = bias[col];
#pragma unroll
      for (int rg = 0; rg < 4; ++rg) {
        int row = orow0 + i * 16 + rg;
        C[(size_t)row * N_TOT + col] = acc[i][j][rg] + bv;
      }
    }
  }
}

extern "C" void kernel_launch(void* const* d_in, const int* in_sizes, int n_in,
                              void* d_out, int out_size, void* d_ws,
                              size_t ws_size, hipStream_t stream) {
  const float* x = (const float*)d_in[0];
  const float* W = (const float*)d_in[1];
  const float* b = (const float*)d_in[2];
  float* out = (float*)d_out;

  const size_t xq_bytes = (size_t)M_TOT * K_TOT;           // 33.5 MB
  const size_t wq_bytes = (size_t)N_TOT * K_TOT;           // 67.1 MB
  const size_t need = xq_bytes + wq_bytes + M_TOT * 4;     // ~101 MB

  if (ws_size >= need) {
    char* xq = (char*)d_ws;
    char* wq = xq + xq_bytes;
    float* s = (float*)(wq + wq_bytes);
    quant_x_kernel<<<M_TOT, 256, 0, stream>>>(x, xq, s);
    quant_w_kernel<<<2048, 256, 0, stream>>>(W, wq, (int)(wq_bytes / 4));
    const int nblocks = (M_TOT / BM) * (N_TOT / BN);  // 4096
    gemm_i8_dual<<<nblocks, 512, 0, stream>>>(xq, wq, s, b, out);
  } else {
    const int nblocks = (M_TOT / 128) * (N_TOT / 128);
    gemm_fused_kernel<<<nblocks, 256, 0, stream>>>(x, W, b, out);
  }
}